// Round 5
// baseline (369.517 us; speedup 1.0000x reference)
//
#include <hip/hip_runtime.h>
#include <math.h>

#define D   128
#define DP  64
#define H   8
#define DH  16
#define DO  32
#define NB  2
#define L   320
#define NR  (NB * L)   // 640 rows

typedef float f4 __attribute__((ext_vector_type(4)));

// ---------------------------------------------------------------------------
// K1: LayerNorm1 + fused QKV projection. 2 rows per block, 256 threads.
// ---------------------------------------------------------------------------
__global__ __launch_bounds__(256) void k1_ln_qkv(
    const float* __restrict__ x, const float* __restrict__ Wq,
    const float* __restrict__ Wk, const float* __restrict__ Wv,
    const float* __restrict__ g, const float* __restrict__ bb,
    float* __restrict__ qkv) {
  __shared__ float xs[2][D];
  __shared__ float stat[2][2];
  const int t = threadIdx.x;
  const int r0 = blockIdx.x * 2;
  const int row = t >> 7, c = t & 127;
  xs[row][c] = x[(r0 + row) * D + c];
  __syncthreads();
  const int w = t >> 6, lane = t & 63;
  if (w < 2) {
    float a = xs[w][lane], cc = xs[w][lane + 64];
    float s = a + cc, s2 = a * a + cc * cc;
#pragma unroll
    for (int off = 32; off >= 1; off >>= 1) {
      s += __shfl_xor(s, off, 64);
      s2 += __shfl_xor(s2, off, 64);
    }
    if (lane == 0) {
      float mu = s * (1.0f / D);
      float var = s2 * (1.0f / D) - mu * mu;
      stat[w][0] = mu;
      stat[w][1] = rsqrtf(var + 1e-5f);
    }
  }
  __syncthreads();
  float xn = (xs[row][c] - stat[row][0]) * stat[row][1] * g[c] + bb[c];
  xs[row][c] = xn;
  __syncthreads();
  float aq = 0, ak = 0, av = 0;
#pragma unroll 4
  for (int k = 0; k < D; ++k) {
    float wq = Wq[k * D + c], wk = Wk[k * D + c], wv = Wv[k * D + c];
    float xv = xs[row][k];
    aq += xv * wq;
    ak += xv * wk;
    av += xv * wv;
  }
  int base = (r0 + row) * 384 + c;
  qkv[base] = aq;
  qkv[base + 128] = ak;
  qkv[base + 256] = av;
}

// ---------------------------------------------------------------------------
// K2: bias[b,h,i,j] = sum_p z[b,i,j,p] * Wb[p,h].  Tile of 64 j's per block.
// ---------------------------------------------------------------------------
__global__ __launch_bounds__(256) void k2_bias(
    const float* __restrict__ z, const float* __restrict__ Wb,
    float* __restrict__ bias) {
  __shared__ float zs[64][65];
  __shared__ float wbs[DP * H];
  const int t = threadIdx.x;
  const int jt = blockIdx.x, i = blockIdx.y, b = blockIdx.z;
  const f4* zsrc4 =
      (const f4*)(z + (((size_t)(b * L + i) * L) + jt * 64) * DP);
#pragma unroll
  for (int q = 0; q < 4; ++q) {
    int idx4 = q * 256 + t;
    f4 v = zsrc4[idx4];          // plain load — L2 does the coalescing
    int r = idx4 >> 4, c0 = (idx4 & 15) * 4;
    zs[r][c0] = v.x; zs[r][c0 + 1] = v.y; zs[r][c0 + 2] = v.z; zs[r][c0 + 3] = v.w;
  }
  for (int q = t; q < DP * H; q += 256) wbs[q] = Wb[q];
  __syncthreads();
  const int h0 = t >> 6, j = t & 63;
  float a0 = 0, a1 = 0;
#pragma unroll 8
  for (int p = 0; p < 64; ++p) {
    float zv = zs[j][p];
    a0 += zv * wbs[p * H + h0];
    a1 += zv * wbs[p * H + h0 + 4];
  }
  size_t o0 = (((size_t)(b * H + h0) * L) + i) * L + jt * 64 + j;
  bias[o0] = a0;
  bias[o0 + (size_t)4 * L * L] = a1;
}

// ---------------------------------------------------------------------------
// K3: attention per (b,h, i-tile of 16).  1024 threads, one row per wave.
// ---------------------------------------------------------------------------
__global__ __launch_bounds__(1024, 8) void k3_attn(
    const float* __restrict__ qkv, const float* __restrict__ bias,
    float* __restrict__ ao) {
  __shared__ float Ks[L * 17];
  __shared__ float Vs[L * 17];
  __shared__ float qs[16 * DH];
  __shared__ float ps[16][L];
  const int t = threadIdx.x;
  const int i0 = blockIdx.x * 16, h = blockIdx.y, b = blockIdx.z;
  for (int idx = t; idx < L * DH; idx += 1024) {
    int j = idx >> 4, d = idx & 15;
    const float* src = qkv + (size_t)(b * L + j) * 384 + h * DH + d;
    Ks[j * 17 + d] = src[128];
    Vs[j * 17 + d] = src[256];
  }
  if (t < 256) {
    int ii = t >> 4, d = t & 15;
    qs[t] = qkv[(size_t)(b * L + i0 + ii) * 384 + h * DH + d] * 0.25f; // 1/sqrt(16)
  }
  __syncthreads();
  const int w = t >> 6, lane = t & 63;
  const int i = i0 + w;   // one row per wave
  const float* brow = bias + (((size_t)(b * H + h) * L) + i) * L;
  float sc[5], m = -1e30f;
#pragma unroll
  for (int it = 0; it < 5; ++it) {
    int j = it * 64 + lane;
    float s = 0;
#pragma unroll
    for (int d = 0; d < DH; ++d) s += qs[w * DH + d] * Ks[j * 17 + d];
    s += brow[j];
    sc[it] = s;
    m = fmaxf(m, s);
  }
#pragma unroll
  for (int off = 32; off >= 1; off >>= 1) m = fmaxf(m, __shfl_xor(m, off, 64));
  float sum = 0;
#pragma unroll
  for (int it = 0; it < 5; ++it) {
    sc[it] = __expf(sc[it] - m);
    sum += sc[it];
  }
#pragma unroll
  for (int off = 32; off >= 1; off >>= 1) sum += __shfl_xor(sum, off, 64);
  float inv = 1.0f / sum;
#pragma unroll
  for (int it = 0; it < 5; ++it) ps[w][it * 64 + lane] = sc[it];
  // wave-internal LDS RAW: DS ops in-order within a wave, no barrier needed
  int d = lane & 15, grp = lane >> 4;
  float acc = 0;
#pragma unroll 4
  for (int j = grp * 80; j < grp * 80 + 80; ++j) acc += ps[w][j] * Vs[j * 17 + d];
  acc += __shfl_xor(acc, 16, 64);
  acc += __shfl_xor(acc, 32, 64);
  if (lane < 16) ao[(size_t)(b * L + i) * D + h * DH + d] = acc * inv;
}

// ---------------------------------------------------------------------------
// K45: fused per-2-row pass: Wo+res -> LN2 -> FFN(gelu)+res -> x out ->
//      p1/p2 -> T = p1 @ Wz4.  512 threads; float4 weight loads everywhere.
// ---------------------------------------------------------------------------
__global__ __launch_bounds__(512, 4) void k45_rowpass(
    const float* __restrict__ x, const float* __restrict__ ao,
    const float* __restrict__ Wo, const float* __restrict__ bo,
    const float* __restrict__ g2, const float* __restrict__ b2,
    const float* __restrict__ W1, const float* __restrict__ bf1,
    const float* __restrict__ W2, const float* __restrict__ bf2,
    const float* __restrict__ Wp1, const float* __restrict__ bp1,
    const float* __restrict__ Wp2, const float* __restrict__ bp2,
    const float* __restrict__ Wz,
    float* __restrict__ out_x, float* __restrict__ p1, float* __restrict__ p2,
    float* __restrict__ T) {
  __shared__ float aos[2][D];
  __shared__ float x1s[2][D];
  __shared__ float nrm[2][D];
  __shared__ float x2s[2][D];
  __shared__ float hs[2][512];
  __shared__ __align__(16) float redbuf[4096];   // 16 KB, reused per phase
  __shared__ float ps_row[2][64];
  __shared__ float stat[2][2];
  f4* red4 = (f4*)redbuf;
  const int t = threadIdx.x;
  const int r0 = blockIdx.x * 2;
  // P1: load ao rows
  if (t < 256) { int r = t >> 7, c = t & 127; aos[r][c] = ao[(r0 + r) * D + c]; }
  __syncthreads();
  // P2: Wo partials — 32 col-groups(x4) × 16 k-chunks(of 8)
  {
    int cg = t & 31, q = t >> 5;
    f4 a0 = {0, 0, 0, 0}, a1 = {0, 0, 0, 0};
#pragma unroll
    for (int k = q * 8; k < q * 8 + 8; ++k) {
      f4 wv = ((const f4*)(Wo + k * D))[cg];
      float v0 = aos[0][k], v1 = aos[1][k];
      a0 += v0 * wv;
      a1 += v1 * wv;
    }
    red4[(q * 2 + 0) * 32 + cg] = a0;
    red4[(q * 2 + 1) * 32 + cg] = a1;
  }
  __syncthreads();
  // P3: x1 = x + Wo-proj + bo
  if (t < 256) {
    int r = t >> 7, c = t & 127;
    float a = x[(r0 + r) * D + c] + bo[c];
#pragma unroll
    for (int q = 0; q < 16; ++q) a += redbuf[q * 256 + r * 128 + c];
    x1s[r][c] = a;
  }
  __syncthreads();
  // P4: LN2 stats (wave w handles row w)
  if (t < 128) {
    int w = t >> 6, lane = t & 63;
    float a = x1s[w][lane], cc = x1s[w][lane + 64];
    float s = a + cc, s2 = a * a + cc * cc;
#pragma unroll
    for (int off = 32; off >= 1; off >>= 1) {
      s += __shfl_xor(s, off, 64);
      s2 += __shfl_xor(s2, off, 64);
    }
    if (lane == 0) {
      float mu = s * (1.0f / D);
      stat[w][0] = mu;
      stat[w][1] = rsqrtf(s2 * (1.0f / D) - mu * mu + 1e-5f);
    }
  }
  __syncthreads();
  // P5: normalize
  if (t < 256) {
    int r = t >> 7, c = t & 127;
    nrm[r][c] = (x1s[r][c] - stat[r][0]) * stat[r][1] * g2[c] + b2[c];
  }
  __syncthreads();
  // P6: FFN1 partials — 128 col-groups(x4) × 4 k-chunks(of 32)
  {
    int cg = t & 127, q = t >> 7;
    f4 a0 = {0, 0, 0, 0}, a1 = {0, 0, 0, 0};
#pragma unroll 4
    for (int k = q * 32; k < q * 32 + 32; ++k) {
      f4 wv = ((const f4*)(W1 + k * 512))[cg];
      float v0 = nrm[0][k], v1 = nrm[1][k];
      a0 += v0 * wv;
      a1 += v1 * wv;
    }
    red4[q * 256 + 0 * 128 + cg] = a0;
    red4[q * 256 + 1 * 128 + cg] = a1;
  }
  __syncthreads();
  // P7: reduce + gelu -> hs
  {
#pragma unroll
    for (int r = 0; r < 2; ++r) {
      float a = bf1[t];
#pragma unroll
      for (int q = 0; q < 4; ++q) a += redbuf[q * 1024 + r * 512 + t];
      hs[r][t] = 0.5f * a * (1.0f + erff(a * 0.70710678118654752f));
    }
  }
  __syncthreads();
  // P8: FFN2 partials — 32 col-groups(x4) × 16 k-chunks(of 32)
  {
    int cg = t & 31, q = t >> 5;
    f4 a0 = {0, 0, 0, 0}, a1 = {0, 0, 0, 0};
#pragma unroll 4
    for (int k = q * 32; k < q * 32 + 32; ++k) {
      f4 wv = ((const f4*)(W2 + k * D))[cg];
      float v0 = hs[0][k], v1 = hs[1][k];
      a0 += v0 * wv;
      a1 += v1 * wv;
    }
    red4[(q * 2 + 0) * 32 + cg] = a0;
    red4[(q * 2 + 1) * 32 + cg] = a1;
  }
  __syncthreads();
  // P9: x2 = x1 + FFN2 + bf2 ; write out_x
  if (t < 256) {
    int r = t >> 7, c = t & 127;
    float a = x1s[r][c] + bf2[c];
#pragma unroll
    for (int q = 0; q < 16; ++q) a += redbuf[q * 256 + r * 128 + c];
    x2s[r][c] = a;
    out_x[(r0 + r) * D + c] = a;
  }
  __syncthreads();
  // P10: p1/p2 partials — t = q*128 + r*64 + o, k-chunk of 32
  {
    int o = t & 63, r = (t >> 6) & 1, q = t >> 7;
    const float* W = (o < 32) ? Wp1 : Wp2;
    int cc = o & 31;
    float a = 0;
#pragma unroll
    for (int k = q * 32; k < q * 32 + 32; ++k) a += x2s[r][k] * W[k * DO + cc];
    redbuf[t] = a;
  }
  __syncthreads();
  // P11: reduce p-proj, write p1/p2, keep in LDS
  if (t < 128) {
    int r = t >> 6, o = t & 63;
    float a = redbuf[0 * 128 + r * 64 + o] + redbuf[1 * 128 + r * 64 + o] +
              redbuf[2 * 128 + r * 64 + o] + redbuf[3 * 128 + r * 64 + o] +
              ((o < 32) ? bp1[o] : bp2[o & 31]);
    ps_row[r][o] = a;
    if (o < 32) p1[(r0 + r) * DO + o] = a;
    else        p2[(r0 + r) * DO + (o & 31)] = a;
  }
  __syncthreads();
  // P12: T[r, idx] = sum_c p1[r][c] * Wz[c][idx] — float4 over idx
  {
    const f4* Wz4 = (const f4*)Wz;
    f4 a0 = {0, 0, 0, 0}, a1 = {0, 0, 0, 0};
#pragma unroll 8
    for (int cc = 0; cc < 32; ++cc) {
      f4 wv = Wz4[cc * 512 + t];
      float v0 = ps_row[0][cc], v1 = ps_row[1][cc];
      a0 += v0 * wv;
      a1 += v1 * wv;
    }
    ((f4*)T)[(size_t)(r0 + 0) * 512 + t] = a0;
    ((f4*)T)[(size_t)(r0 + 1) * 512 + t] = a1;
  }
}

// ---------------------------------------------------------------------------
// K6: z_out = LN(z + p2 @ T_i + bz).  Block per (b,i,j-tile of 80); lane = p.
// 4-way j-unroll, software-pipelined plain z loads (L2 coalesces; NT was an
// 8x write-amplification disaster — never NT with <16B/lane).
// ---------------------------------------------------------------------------
__global__ __launch_bounds__(256, 5) void k6_zout(
    const float* __restrict__ z, const float* __restrict__ T,
    const float* __restrict__ p2, const float* __restrict__ bz,
    const float* __restrict__ gp, const float* __restrict__ bp,
    float* __restrict__ zout) {
  __shared__ __align__(16) float p2s[80 * DO];  // 10 KB
  const int t = threadIdx.x;
  const int jt = blockIdx.x;
  const int i = blockIdx.y, b = blockIdx.z;
  const size_t row = (size_t)(b * L + i);
  {
    const f4* psrc4 = (const f4*)(p2 + ((size_t)b * L + jt * 80) * DO);
    f4* p2s4 = (f4*)p2s;
    for (int q = t; q < 640; q += 256) p2s4[q] = psrc4[q];
  }
  const int w = t >> 6, lane = t & 63;
  float treg[32];
#pragma unroll
  for (int d = 0; d < 32; ++d) treg[d] = T[row * 2048 + d * 64 + lane];
  const float bzv = bz[lane], gv = gp[lane], bv = bp[lane];
  __syncthreads();
  const float* zrow = z + (row * L + (size_t)jt * 80) * DP;
  float* orow = zout + (row * L + (size_t)jt * 80) * DP;
  const int jb = w * 20;
  float zv0 = zrow[(jb + 0) * DP + lane];
  float zv1 = zrow[(jb + 1) * DP + lane];
  float zv2 = zrow[(jb + 2) * DP + lane];
  float zv3 = zrow[(jb + 3) * DP + lane];
#pragma unroll
  for (int g = 0; g < 5; ++g) {
    const int j0 = jb + g * 4;
    const f4* pj0 = (const f4*)&p2s[(j0 + 0) * DO];
    const f4* pj1 = (const f4*)&p2s[(j0 + 1) * DO];
    const f4* pj2 = (const f4*)&p2s[(j0 + 2) * DO];
    const f4* pj3 = (const f4*)&p2s[(j0 + 3) * DO];
    float u0 = bzv, u1 = bzv, u2 = bzv, u3 = bzv;
#pragma unroll
    for (int dd = 0; dd < 8; ++dd) {
      float t0 = treg[dd * 4], t1 = treg[dd * 4 + 1];
      float t2 = treg[dd * 4 + 2], t3 = treg[dd * 4 + 3];
      f4 a0 = pj0[dd], a1 = pj1[dd], a2 = pj2[dd], a3 = pj3[dd];
      u0 += a0.x * t0 + a0.y * t1 + a0.z * t2 + a0.w * t3;
      u1 += a1.x * t0 + a1.y * t1 + a1.z * t2 + a1.w * t3;
      u2 += a2.x * t0 + a2.y * t1 + a2.z * t2 + a2.w * t3;
      u3 += a3.x * t0 + a3.y * t1 + a3.z * t2 + a3.w * t3;
    }
    float y0 = zv0 + u0, y1 = zv1 + u1, y2 = zv2 + u2, y3 = zv3 + u3;
    if (g < 4) {  // prefetch next group under the reduce chain
      zv0 = zrow[(j0 + 4) * DP + lane];
      zv1 = zrow[(j0 + 5) * DP + lane];
      zv2 = zrow[(j0 + 6) * DP + lane];
      zv3 = zrow[(j0 + 7) * DP + lane];
    }
    float s0 = y0, q0 = y0 * y0, s1 = y1, q1 = y1 * y1;
    float s2 = y2, q2 = y2 * y2, s3 = y3, q3 = y3 * y3;
#pragma unroll
    for (int off = 32; off >= 1; off >>= 1) {
      s0 += __shfl_xor(s0, off, 64); q0 += __shfl_xor(q0, off, 64);
      s1 += __shfl_xor(s1, off, 64); q1 += __shfl_xor(q1, off, 64);
      s2 += __shfl_xor(s2, off, 64); q2 += __shfl_xor(q2, off, 64);
      s3 += __shfl_xor(s3, off, 64); q3 += __shfl_xor(q3, off, 64);
    }
    float mu0 = s0 * (1.0f / DP), va0 = q0 * (1.0f / DP) - mu0 * mu0;
    float mu1 = s1 * (1.0f / DP), va1 = q1 * (1.0f / DP) - mu1 * mu1;
    float mu2 = s2 * (1.0f / DP), va2 = q2 * (1.0f / DP) - mu2 * mu2;
    float mu3 = s3 * (1.0f / DP), va3 = q3 * (1.0f / DP) - mu3 * mu3;
    orow[(j0 + 0) * DP + lane] = (y0 - mu0) * rsqrtf(va0 + 1e-5f) * gv + bv;
    orow[(j0 + 1) * DP + lane] = (y1 - mu1) * rsqrtf(va1 + 1e-5f) * gv + bv;
    orow[(j0 + 2) * DP + lane] = (y2 - mu2) * rsqrtf(va2 + 1e-5f) * gv + bv;
    orow[(j0 + 3) * DP + lane] = (y3 - mu3) * rsqrtf(va3 + 1e-5f) * gv + bv;
  }
}

// ---------------------------------------------------------------------------
extern "C" void kernel_launch(void* const* d_in, const int* in_sizes, int n_in,
                              void* d_out, int out_size, void* d_ws, size_t ws_size,
                              hipStream_t stream) {
  const float* x      = (const float*)d_in[0];
  const float* z      = (const float*)d_in[1];
  const float* Wq     = (const float*)d_in[2];
  const float* Wk     = (const float*)d_in[3];
  const float* Wv     = (const float*)d_in[4];
  const float* Wb     = (const float*)d_in[5];
  const float* Wo     = (const float*)d_in[6];
  const float* bo     = (const float*)d_in[7];
  const float* ln1_g  = (const float*)d_in[8];
  const float* ln1_b  = (const float*)d_in[9];
  const float* W_ffn1 = (const float*)d_in[10];
  const float* b_ffn1 = (const float*)d_in[11];
  const float* W_ffn2 = (const float*)d_in[12];
  const float* b_ffn2 = (const float*)d_in[13];
  const float* ln2_g  = (const float*)d_in[14];
  const float* ln2_b  = (const float*)d_in[15];
  const float* Wp1    = (const float*)d_in[16];
  const float* bp1    = (const float*)d_in[17];
  const float* Wp2    = (const float*)d_in[18];
  const float* bp2    = (const float*)d_in[19];
  const float* Wz     = (const float*)d_in[20];
  const float* bz     = (const float*)d_in[21];
  const float* lnp_g  = (const float*)d_in[22];
  const float* lnp_b  = (const float*)d_in[23];

  float* ws   = (float*)d_ws;
  float* qkv  = ws;                   // 640*384
  float* bias = qkv + 245760;         // 2*8*320*320
  float* ao   = bias + 1638400;       // 640*128
  float* p1   = ao + 81920;           // 640*32
  float* p2   = p1 + 20480;           // 640*32
  float* T    = p2 + 20480;           // 640*2048

  float* out_x = (float*)d_out;
  float* out_z = out_x + 81920;

  hipLaunchKernelGGL(k1_ln_qkv, dim3(NR / 2), dim3(256), 0, stream,
                     x, Wq, Wk, Wv, ln1_g, ln1_b, qkv);
  hipLaunchKernelGGL(k2_bias, dim3(L / 64, L, NB), dim3(256), 0, stream,
                     z, Wb, bias);
  hipLaunchKernelGGL(k3_attn, dim3(L / 16, H, NB), dim3(1024), 0, stream,
                     qkv, bias, ao);
  hipLaunchKernelGGL(k45_rowpass, dim3(NR / 2), dim3(512), 0, stream,
                     x, ao, Wo, bo, ln2_g, ln2_b, W_ffn1, b_ffn1,
                     W_ffn2, b_ffn2, Wp1, bp1, Wp2, bp2, Wz, out_x, p1, p2, T);
  hipLaunchKernelGGL(k6_zout, dim3(4, L, NB), dim3(256), 0, stream,
                     z, T, p2, bz, lnp_g, lnp_b, out_z);
}

// Round 6
// 207.841 us; speedup vs baseline: 1.7779x; 1.7779x over previous
//
#include <hip/hip_runtime.h>
#include <math.h>

#define D   128
#define DP  64
#define H   8
#define DH  16
#define DO  32
#define NB  2
#define L   320
#define NR  (NB * L)   // 640 rows

typedef float f4 __attribute__((ext_vector_type(4)));

// ---------------------------------------------------------------------------
// K1: LayerNorm1 + fused QKV projection. 2 rows per block, 256 threads.
// ---------------------------------------------------------------------------
__global__ __launch_bounds__(256) void k1_ln_qkv(
    const float* __restrict__ x, const float* __restrict__ Wq,
    const float* __restrict__ Wk, const float* __restrict__ Wv,
    const float* __restrict__ g, const float* __restrict__ bb,
    float* __restrict__ qkv) {
  __shared__ float xs[2][D];
  __shared__ float stat[2][2];
  const int t = threadIdx.x;
  const int r0 = blockIdx.x * 2;
  const int row = t >> 7, c = t & 127;
  xs[row][c] = x[(r0 + row) * D + c];
  __syncthreads();
  const int w = t >> 6, lane = t & 63;
  if (w < 2) {
    float a = xs[w][lane], cc = xs[w][lane + 64];
    float s = a + cc, s2 = a * a + cc * cc;
#pragma unroll
    for (int off = 32; off >= 1; off >>= 1) {
      s += __shfl_xor(s, off, 64);
      s2 += __shfl_xor(s2, off, 64);
    }
    if (lane == 0) {
      float mu = s * (1.0f / D);
      float var = s2 * (1.0f / D) - mu * mu;
      stat[w][0] = mu;
      stat[w][1] = rsqrtf(var + 1e-5f);
    }
  }
  __syncthreads();
  float xn = (xs[row][c] - stat[row][0]) * stat[row][1] * g[c] + bb[c];
  xs[row][c] = xn;
  __syncthreads();
  float aq = 0, ak = 0, av = 0;
#pragma unroll 4
  for (int k = 0; k < D; ++k) {
    float wq = Wq[k * D + c], wk = Wk[k * D + c], wv = Wv[k * D + c];
    float xv = xs[row][k];
    aq += xv * wq;
    ak += xv * wk;
    av += xv * wv;
  }
  int base = (r0 + row) * 384 + c;
  qkv[base] = aq;
  qkv[base + 128] = ak;
  qkv[base + 256] = av;
}

// ---------------------------------------------------------------------------
// K2: bias[b,h,i,j] = sum_p z[b,i,j,p] * Wb[p,h].  Tile of 64 j's per block.
// ---------------------------------------------------------------------------
__global__ __launch_bounds__(256) void k2_bias(
    const float* __restrict__ z, const float* __restrict__ Wb,
    float* __restrict__ bias) {
  __shared__ float zs[64][65];
  __shared__ float wbs[DP * H];
  const int t = threadIdx.x;
  const int jt = blockIdx.x, i = blockIdx.y, b = blockIdx.z;
  const f4* zsrc4 =
      (const f4*)(z + (((size_t)(b * L + i) * L) + jt * 64) * DP);
#pragma unroll
  for (int q = 0; q < 4; ++q) {
    int idx4 = q * 256 + t;
    f4 v = zsrc4[idx4];
    int r = idx4 >> 4, c0 = (idx4 & 15) * 4;
    zs[r][c0] = v.x; zs[r][c0 + 1] = v.y; zs[r][c0 + 2] = v.z; zs[r][c0 + 3] = v.w;
  }
  for (int q = t; q < DP * H; q += 256) wbs[q] = Wb[q];
  __syncthreads();
  const int h0 = t >> 6, j = t & 63;
  float a0 = 0, a1 = 0;
#pragma unroll 8
  for (int p = 0; p < 64; ++p) {
    float zv = zs[j][p];
    a0 += zv * wbs[p * H + h0];
    a1 += zv * wbs[p * H + h0 + 4];
  }
  size_t o0 = (((size_t)(b * H + h0) * L) + i) * L + jt * 64 + j;
  bias[o0] = a0;
  bias[o0 + (size_t)4 * L * L] = a1;
}

// ---------------------------------------------------------------------------
// K3: attention per (b,h, i-tile of 16).  1024 threads, one row per wave.
// ---------------------------------------------------------------------------
__global__ __launch_bounds__(1024, 8) void k3_attn(
    const float* __restrict__ qkv, const float* __restrict__ bias,
    float* __restrict__ ao) {
  __shared__ float Ks[L * 17];
  __shared__ float Vs[L * 17];
  __shared__ float qs[16 * DH];
  __shared__ float ps[16][L];
  const int t = threadIdx.x;
  const int i0 = blockIdx.x * 16, h = blockIdx.y, b = blockIdx.z;
  for (int idx = t; idx < L * DH; idx += 1024) {
    int j = idx >> 4, d = idx & 15;
    const float* src = qkv + (size_t)(b * L + j) * 384 + h * DH + d;
    Ks[j * 17 + d] = src[128];
    Vs[j * 17 + d] = src[256];
  }
  if (t < 256) {
    int ii = t >> 4, d = t & 15;
    qs[t] = qkv[(size_t)(b * L + i0 + ii) * 384 + h * DH + d] * 0.25f; // 1/sqrt(16)
  }
  __syncthreads();
  const int w = t >> 6, lane = t & 63;
  const int i = i0 + w;   // one row per wave
  const float* brow = bias + (((size_t)(b * H + h) * L) + i) * L;
  float sc[5], m = -1e30f;
#pragma unroll
  for (int it = 0; it < 5; ++it) {
    int j = it * 64 + lane;
    float s = 0;
#pragma unroll
    for (int d = 0; d < DH; ++d) s += qs[w * DH + d] * Ks[j * 17 + d];
    s += brow[j];
    sc[it] = s;
    m = fmaxf(m, s);
  }
#pragma unroll
  for (int off = 32; off >= 1; off >>= 1) m = fmaxf(m, __shfl_xor(m, off, 64));
  float sum = 0;
#pragma unroll
  for (int it = 0; it < 5; ++it) {
    sc[it] = __expf(sc[it] - m);
    sum += sc[it];
  }
#pragma unroll
  for (int off = 32; off >= 1; off >>= 1) sum += __shfl_xor(sum, off, 64);
  float inv = 1.0f / sum;
#pragma unroll
  for (int it = 0; it < 5; ++it) ps[w][it * 64 + lane] = sc[it];
  // wave-internal LDS RAW: DS ops in-order within a wave, no barrier needed
  int d = lane & 15, grp = lane >> 4;
  float acc = 0;
#pragma unroll 4
  for (int j = grp * 80; j < grp * 80 + 80; ++j) acc += ps[w][j] * Vs[j * 17 + d];
  acc += __shfl_xor(acc, 16, 64);
  acc += __shfl_xor(acc, 32, 64);
  if (lane < 16) ao[(size_t)(b * L + i) * D + h * DH + d] = acc * inv;
}

// ---------------------------------------------------------------------------
// K45: fused per-2-row pass: Wo+res -> LN2 -> FFN(gelu)+res -> x out ->
//      p1/p2 -> T = p1 @ Wz4.  512 threads; float4 weight loads everywhere.
// ---------------------------------------------------------------------------
__global__ __launch_bounds__(512, 4) void k45_rowpass(
    const float* __restrict__ x, const float* __restrict__ ao,
    const float* __restrict__ Wo, const float* __restrict__ bo,
    const float* __restrict__ g2, const float* __restrict__ b2,
    const float* __restrict__ W1, const float* __restrict__ bf1,
    const float* __restrict__ W2, const float* __restrict__ bf2,
    const float* __restrict__ Wp1, const float* __restrict__ bp1,
    const float* __restrict__ Wp2, const float* __restrict__ bp2,
    const float* __restrict__ Wz,
    float* __restrict__ out_x, float* __restrict__ p1, float* __restrict__ p2,
    float* __restrict__ T) {
  __shared__ float aos[2][D];
  __shared__ float x1s[2][D];
  __shared__ float nrm[2][D];
  __shared__ float x2s[2][D];
  __shared__ float hs[2][512];
  __shared__ __align__(16) float redbuf[4096];   // 16 KB, reused per phase
  __shared__ float ps_row[2][64];
  __shared__ float stat[2][2];
  f4* red4 = (f4*)redbuf;
  const int t = threadIdx.x;
  const int r0 = blockIdx.x * 2;
  // P1: load ao rows
  if (t < 256) { int r = t >> 7, c = t & 127; aos[r][c] = ao[(r0 + r) * D + c]; }
  __syncthreads();
  // P2: Wo partials — 32 col-groups(x4) × 16 k-chunks(of 8)
  {
    int cg = t & 31, q = t >> 5;
    f4 a0 = {0, 0, 0, 0}, a1 = {0, 0, 0, 0};
#pragma unroll
    for (int k = q * 8; k < q * 8 + 8; ++k) {
      f4 wv = ((const f4*)(Wo + k * D))[cg];
      float v0 = aos[0][k], v1 = aos[1][k];
      a0 += v0 * wv;
      a1 += v1 * wv;
    }
    red4[(q * 2 + 0) * 32 + cg] = a0;
    red4[(q * 2 + 1) * 32 + cg] = a1;
  }
  __syncthreads();
  // P3: x1 = x + Wo-proj + bo
  if (t < 256) {
    int r = t >> 7, c = t & 127;
    float a = x[(r0 + r) * D + c] + bo[c];
#pragma unroll
    for (int q = 0; q < 16; ++q) a += redbuf[q * 256 + r * 128 + c];
    x1s[r][c] = a;
  }
  __syncthreads();
  // P4: LN2 stats (wave w handles row w)
  if (t < 128) {
    int w = t >> 6, lane = t & 63;
    float a = x1s[w][lane], cc = x1s[w][lane + 64];
    float s = a + cc, s2 = a * a + cc * cc;
#pragma unroll
    for (int off = 32; off >= 1; off >>= 1) {
      s += __shfl_xor(s, off, 64);
      s2 += __shfl_xor(s2, off, 64);
    }
    if (lane == 0) {
      float mu = s * (1.0f / D);
      stat[w][0] = mu;
      stat[w][1] = rsqrtf(s2 * (1.0f / D) - mu * mu + 1e-5f);
    }
  }
  __syncthreads();
  // P5: normalize
  if (t < 256) {
    int r = t >> 7, c = t & 127;
    nrm[r][c] = (x1s[r][c] - stat[r][0]) * stat[r][1] * g2[c] + b2[c];
  }
  __syncthreads();
  // P6: FFN1 partials — 128 col-groups(x4) × 4 k-chunks(of 32)
  {
    int cg = t & 127, q = t >> 7;
    f4 a0 = {0, 0, 0, 0}, a1 = {0, 0, 0, 0};
#pragma unroll 4
    for (int k = q * 32; k < q * 32 + 32; ++k) {
      f4 wv = ((const f4*)(W1 + k * 512))[cg];
      float v0 = nrm[0][k], v1 = nrm[1][k];
      a0 += v0 * wv;
      a1 += v1 * wv;
    }
    red4[q * 256 + 0 * 128 + cg] = a0;
    red4[q * 256 + 1 * 128 + cg] = a1;
  }
  __syncthreads();
  // P7: reduce + gelu -> hs
  {
#pragma unroll
    for (int r = 0; r < 2; ++r) {
      float a = bf1[t];
#pragma unroll
      for (int q = 0; q < 4; ++q) a += redbuf[q * 1024 + r * 512 + t];
      hs[r][t] = 0.5f * a * (1.0f + erff(a * 0.70710678118654752f));
    }
  }
  __syncthreads();
  // P8: FFN2 partials — 32 col-groups(x4) × 16 k-chunks(of 32)
  {
    int cg = t & 31, q = t >> 5;
    f4 a0 = {0, 0, 0, 0}, a1 = {0, 0, 0, 0};
#pragma unroll 4
    for (int k = q * 32; k < q * 32 + 32; ++k) {
      f4 wv = ((const f4*)(W2 + k * D))[cg];
      float v0 = hs[0][k], v1 = hs[1][k];
      a0 += v0 * wv;
      a1 += v1 * wv;
    }
    red4[(q * 2 + 0) * 32 + cg] = a0;
    red4[(q * 2 + 1) * 32 + cg] = a1;
  }
  __syncthreads();
  // P9: x2 = x1 + FFN2 + bf2 ; write out_x
  if (t < 256) {
    int r = t >> 7, c = t & 127;
    float a = x1s[r][c] + bf2[c];
#pragma unroll
    for (int q = 0; q < 16; ++q) a += redbuf[q * 256 + r * 128 + c];
    x2s[r][c] = a;
    out_x[(r0 + r) * D + c] = a;
  }
  __syncthreads();
  // P10: p1/p2 partials — t = q*128 + r*64 + o, k-chunk of 32
  {
    int o = t & 63, r = (t >> 6) & 1, q = t >> 7;
    const float* W = (o < 32) ? Wp1 : Wp2;
    int cc = o & 31;
    float a = 0;
#pragma unroll
    for (int k = q * 32; k < q * 32 + 32; ++k) a += x2s[r][k] * W[k * DO + cc];
    redbuf[t] = a;
  }
  __syncthreads();
  // P11: reduce p-proj, write p1/p2, keep in LDS
  if (t < 128) {
    int r = t >> 6, o = t & 63;
    float a = redbuf[0 * 128 + r * 64 + o] + redbuf[1 * 128 + r * 64 + o] +
              redbuf[2 * 128 + r * 64 + o] + redbuf[3 * 128 + r * 64 + o] +
              ((o < 32) ? bp1[o] : bp2[o & 31]);
    ps_row[r][o] = a;
    if (o < 32) p1[(r0 + r) * DO + o] = a;
    else        p2[(r0 + r) * DO + (o & 31)] = a;
  }
  __syncthreads();
  // P12: T[r, idx] = sum_c p1[r][c] * Wz[c][idx] — float4 over idx
  {
    const f4* Wz4 = (const f4*)Wz;
    f4 a0 = {0, 0, 0, 0}, a1 = {0, 0, 0, 0};
#pragma unroll 8
    for (int cc = 0; cc < 32; ++cc) {
      f4 wv = Wz4[cc * 512 + t];
      float v0 = ps_row[0][cc], v1 = ps_row[1][cc];
      a0 += v0 * wv;
      a1 += v1 * wv;
    }
    ((f4*)T)[(size_t)(r0 + 0) * 512 + t] = a0;
    ((f4*)T)[(size_t)(r0 + 1) * 512 + t] = a1;
  }
}

// ---------------------------------------------------------------------------
// K6: z_out = LN(z + p2 @ T_i + bz).  Block per (b,i,j-tile of 80).
// NEW LAYOUT: lane = (jj,pq) — each lane owns 4 consecutive p's of one j.
// All z/zout accesses are f4 (16B/lane); T lives in LDS (8KB) not registers
// (round-3's treg[32]+4-way unroll spilled to scratch: 450MB phantom traffic).
// LN reduce = 4 shuffle steps across the 16-lane group. ~40 VGPRs live.
// ---------------------------------------------------------------------------
__global__ __launch_bounds__(256) void k6_zout(
    const float* __restrict__ z, const float* __restrict__ T,
    const float* __restrict__ p2, const float* __restrict__ bz,
    const float* __restrict__ gp, const float* __restrict__ bp,
    float* __restrict__ zout) {
  __shared__ __align__(16) f4 tds[32][16];       // T[d][p4]: 8 KB
  __shared__ __align__(16) float p2s[80 * DO];   // 10 KB
  const int t = threadIdx.x;
  const int jt = blockIdx.x;       // 0..3: tile of 80 j's
  const int i = blockIdx.y, b = blockIdx.z;
  const size_t row = (size_t)(b * L + i);
  {  // stage T row (512 f4) and p2 tile (640 f4)
    const f4* Tsrc = (const f4*)(T + row * 2048);
    f4* tflat = (f4*)tds;
    tflat[t] = Tsrc[t];
    tflat[t + 256] = Tsrc[t + 256];
    const f4* psrc4 = (const f4*)(p2 + ((size_t)b * L + jt * 80) * DO);
    f4* p2s4 = (f4*)p2s;
    for (int q = t; q < 640; q += 256) p2s4[q] = psrc4[q];
  }
  const int w = t >> 6, lane = t & 63;
  const int jj = lane >> 4, pq = lane & 15;
  const f4 bz4 = ((const f4*)bz)[pq];
  const f4 g4 = ((const f4*)gp)[pq];
  const f4 b4 = ((const f4*)bp)[pq];
  __syncthreads();
  const float* zbase = z + (row * L + (size_t)jt * 80) * DP;
  float* obase = zout + (row * L + (size_t)jt * 80) * DP;
#pragma unroll
  for (int q = 0; q < 5; ++q) {
    const int jl = w * 20 + q * 4 + jj;          // local j in [0,80)
    f4 zv = ((const f4*)(zbase + jl * DP))[pq];
    f4 acc0 = bz4, acc1 = {0, 0, 0, 0};
#pragma unroll
    for (int d = 0; d < 32; d += 2) {
      acc0 += p2s[jl * DO + d] * tds[d][pq];
      acc1 += p2s[jl * DO + d + 1] * tds[d + 1][pq];
    }
    f4 y = zv + acc0 + acc1;
    float s = y.x + y.y + y.z + y.w;
    float s2 = y.x * y.x + y.y * y.y + y.z * y.z + y.w * y.w;
#pragma unroll
    for (int off = 8; off >= 1; off >>= 1) {     // reduce across 16-lane group
      s += __shfl_xor(s, off, 64);
      s2 += __shfl_xor(s2, off, 64);
    }
    float mu = s * (1.0f / DP);
    float var = s2 * (1.0f / DP) - mu * mu;
    float r = rsqrtf(var + 1e-5f);
    f4 out = (y - mu) * r * g4 + b4;
    ((f4*)(obase + jl * DP))[pq] = out;
  }
}

// ---------------------------------------------------------------------------
extern "C" void kernel_launch(void* const* d_in, const int* in_sizes, int n_in,
                              void* d_out, int out_size, void* d_ws, size_t ws_size,
                              hipStream_t stream) {
  const float* x      = (const float*)d_in[0];
  const float* z      = (const float*)d_in[1];
  const float* Wq     = (const float*)d_in[2];
  const float* Wk     = (const float*)d_in[3];
  const float* Wv     = (const float*)d_in[4];
  const float* Wb     = (const float*)d_in[5];
  const float* Wo     = (const float*)d_in[6];
  const float* bo     = (const float*)d_in[7];
  const float* ln1_g  = (const float*)d_in[8];
  const float* ln1_b  = (const float*)d_in[9];
  const float* W_ffn1 = (const float*)d_in[10];
  const float* b_ffn1 = (const float*)d_in[11];
  const float* W_ffn2 = (const float*)d_in[12];
  const float* b_ffn2 = (const float*)d_in[13];
  const float* ln2_g  = (const float*)d_in[14];
  const float* ln2_b  = (const float*)d_in[15];
  const float* Wp1    = (const float*)d_in[16];
  const float* bp1    = (const float*)d_in[17];
  const float* Wp2    = (const float*)d_in[18];
  const float* bp2    = (const float*)d_in[19];
  const float* Wz     = (const float*)d_in[20];
  const float* bz     = (const float*)d_in[21];
  const float* lnp_g  = (const float*)d_in[22];
  const float* lnp_b  = (const float*)d_in[23];

  float* ws   = (float*)d_ws;
  float* qkv  = ws;                   // 640*384
  float* bias = qkv + 245760;         // 2*8*320*320
  float* ao   = bias + 1638400;       // 640*128
  float* p1   = ao + 81920;           // 640*32
  float* p2   = p1 + 20480;           // 640*32
  float* T    = p2 + 20480;           // 640*2048

  float* out_x = (float*)d_out;
  float* out_z = out_x + 81920;

  hipLaunchKernelGGL(k1_ln_qkv, dim3(NR / 2), dim3(256), 0, stream,
                     x, Wq, Wk, Wv, ln1_g, ln1_b, qkv);
  hipLaunchKernelGGL(k2_bias, dim3(L / 64, L, NB), dim3(256), 0, stream,
                     z, Wb, bias);
  hipLaunchKernelGGL(k3_attn, dim3(L / 16, H, NB), dim3(1024), 0, stream,
                     qkv, bias, ao);
  hipLaunchKernelGGL(k45_rowpass, dim3(NR / 2), dim3(512), 0, stream,
                     x, ao, Wo, bo, ln2_g, ln2_b, W_ffn1, b_ffn1,
                     W_ffn2, b_ffn2, Wp1, bp1, Wp2, bp2, Wz, out_x, p1, p2, T);
  hipLaunchKernelGGL(k6_zout, dim3(4, L, NB), dim3(256), 0, stream,
                     z, T, p2, bz, lnp_g, lnp_b, out_z);
}

// Round 7
// 204.038 us; speedup vs baseline: 1.8110x; 1.0186x over previous
//
#include <hip/hip_runtime.h>
#include <math.h>

#define D   128
#define DP  64
#define H   8
#define DH  16
#define DO  32
#define NB  2
#define L   320
#define NR  (NB * L)   // 640 rows

typedef float f4 __attribute__((ext_vector_type(4)));

// ---------------------------------------------------------------------------
// K12: fused independent front-end.
//   blocks [0,320):   LayerNorm1 + QKV projection (2 rows per block)
//   blocks [320,3520): bias[b,h,i,j] = sum_p z[b,i,j,p] * Wb[p,h]
// Merged so k1's latency-bound blocks overlap k2's bandwidth-bound blocks.
// ---------------------------------------------------------------------------
__global__ __launch_bounds__(256) void k12_qkv_bias(
    const float* __restrict__ x, const float* __restrict__ Wq,
    const float* __restrict__ Wk, const float* __restrict__ Wv,
    const float* __restrict__ g, const float* __restrict__ bb,
    float* __restrict__ qkv,
    const float* __restrict__ z, const float* __restrict__ Wb,
    float* __restrict__ bias) {
  __shared__ float zs[64][65];          // k2 tile (k1 reuses first 2*128+4)
  __shared__ float wbs[DP * H];
  const int t = threadIdx.x;
  if (blockIdx.x < 320) {
    // ---- k1: LN1 + QKV, rows r0, r0+1 ----
    float* xs = &zs[0][0];              // [2][128]
    float* stat = &wbs[0];              // [2][2]
    const int r0 = blockIdx.x * 2;
    const int row = t >> 7, c = t & 127;
    xs[row * D + c] = x[(r0 + row) * D + c];
    __syncthreads();
    const int w = t >> 6, lane = t & 63;
    if (w < 2) {
      float a = xs[w * D + lane], cc = xs[w * D + lane + 64];
      float s = a + cc, s2 = a * a + cc * cc;
#pragma unroll
      for (int off = 32; off >= 1; off >>= 1) {
        s += __shfl_xor(s, off, 64);
        s2 += __shfl_xor(s2, off, 64);
      }
      if (lane == 0) {
        float mu = s * (1.0f / D);
        float var = s2 * (1.0f / D) - mu * mu;
        stat[w * 2 + 0] = mu;
        stat[w * 2 + 1] = rsqrtf(var + 1e-5f);
      }
    }
    __syncthreads();
    float xn = (xs[row * D + c] - stat[row * 2]) * stat[row * 2 + 1] * g[c] + bb[c];
    __syncthreads();                    // xs re-write below, keep ordered
    xs[row * D + c] = xn;
    __syncthreads();
    float aq = 0, ak = 0, av = 0;
#pragma unroll 4
    for (int k = 0; k < D; ++k) {
      float wq = Wq[k * D + c], wk = Wk[k * D + c], wv = Wv[k * D + c];
      float xv = xs[row * D + k];
      aq += xv * wq;
      ak += xv * wk;
      av += xv * wv;
    }
    int base = (r0 + row) * 384 + c;
    qkv[base] = aq;
    qkv[base + 128] = ak;
    qkv[base + 256] = av;
  } else {
    // ---- k2: bias tile ----
    const int bi = blockIdx.x - 320;
    const int jt = bi % 5;
    const int i = (bi / 5) % L;
    const int b = bi / (5 * L);
    const f4* zsrc4 =
        (const f4*)(z + (((size_t)(b * L + i) * L) + jt * 64) * DP);
#pragma unroll
    for (int q = 0; q < 4; ++q) {
      int idx4 = q * 256 + t;
      f4 v = zsrc4[idx4];
      int r = idx4 >> 4, c0 = (idx4 & 15) * 4;
      zs[r][c0] = v.x; zs[r][c0 + 1] = v.y; zs[r][c0 + 2] = v.z; zs[r][c0 + 3] = v.w;
    }
    for (int q = t; q < DP * H; q += 256) wbs[q] = Wb[q];
    __syncthreads();
    const int h0 = t >> 6, j = t & 63;
    float a0 = 0, a1 = 0;
#pragma unroll 8
    for (int p = 0; p < 64; ++p) {
      float zv = zs[j][p];
      a0 += zv * wbs[p * H + h0];
      a1 += zv * wbs[p * H + h0 + 4];
    }
    size_t o0 = (((size_t)(b * H + h0) * L) + i) * L + jt * 64 + j;
    bias[o0] = a0;
    bias[o0 + (size_t)4 * L * L] = a1;
  }
}

// ---------------------------------------------------------------------------
// K3: attention per (b,h, i-tile of 4).  256 threads, one i-row per wave.
// Grid 1280 blocks (was 160) — occupancy fix; K/V staged via f4 loads.
// ---------------------------------------------------------------------------
__global__ __launch_bounds__(256) void k3_attn(
    const float* __restrict__ qkv, const float* __restrict__ bias,
    float* __restrict__ ao) {
  __shared__ float Ks[L * 17];
  __shared__ float Vs[L * 17];
  __shared__ float qs[4 * DH];
  __shared__ float ps[4][L];
  const int t = threadIdx.x;
  const int i0 = blockIdx.x * 4, h = blockIdx.y, b = blockIdx.z;
  const f4* qkv4 = (const f4*)qkv;
  // stage K and V: 2×1280 f4s; each row of K/V = 4 contiguous f4s
  for (int idx = t; idx < 2560; idx += 256) {
    int isV = idx >= 1280;
    int e = idx - isV * 1280;
    int j = e >> 2, sub = e & 3;
    f4 v = qkv4[(size_t)(b * L + j) * 96 + h * 4 + (isV ? 64 : 32) + sub];
    float* dst = (isV ? Vs : Ks) + j * 17 + sub * 4;
    dst[0] = v.x; dst[1] = v.y; dst[2] = v.z; dst[3] = v.w;
  }
  if (t < 64) {
    int ii = t >> 4, d = t & 15;
    qs[t] = qkv[(size_t)(b * L + i0 + ii) * 384 + h * DH + d] * 0.25f; // 1/sqrt(16)
  }
  __syncthreads();
  const int w = t >> 6, lane = t & 63;
  const int i = i0 + w;   // one row per wave
  const float* brow = bias + (((size_t)(b * H + h) * L) + i) * L;
  float sc[5], m = -1e30f;
#pragma unroll
  for (int it = 0; it < 5; ++it) {
    int j = it * 64 + lane;
    float s = 0;
#pragma unroll
    for (int d = 0; d < DH; ++d) s += qs[w * DH + d] * Ks[j * 17 + d];
    s += brow[j];
    sc[it] = s;
    m = fmaxf(m, s);
  }
#pragma unroll
  for (int off = 32; off >= 1; off >>= 1) m = fmaxf(m, __shfl_xor(m, off, 64));
  float sum = 0;
#pragma unroll
  for (int it = 0; it < 5; ++it) {
    sc[it] = __expf(sc[it] - m);
    sum += sc[it];
  }
#pragma unroll
  for (int off = 32; off >= 1; off >>= 1) sum += __shfl_xor(sum, off, 64);
  float inv = 1.0f / sum;
#pragma unroll
  for (int it = 0; it < 5; ++it) ps[w][it * 64 + lane] = sc[it];
  // wave-internal LDS RAW: DS ops in-order within a wave, no barrier needed
  int d = lane & 15, grp = lane >> 4;
  float acc = 0;
#pragma unroll 4
  for (int j = grp * 80; j < grp * 80 + 80; ++j) acc += ps[w][j] * Vs[j * 17 + d];
  acc += __shfl_xor(acc, 16, 64);
  acc += __shfl_xor(acc, 32, 64);
  if (lane < 16) ao[(size_t)(b * L + i) * D + h * DH + d] = acc * inv;
}

// ---------------------------------------------------------------------------
// K45: fused per-2-row pass: Wo+res -> LN2 -> FFN(gelu)+res -> x out ->
//      p1/p2 -> T = p1 @ Wz4.  512 threads; float4 weight loads everywhere.
// ---------------------------------------------------------------------------
__global__ __launch_bounds__(512, 4) void k45_rowpass(
    const float* __restrict__ x, const float* __restrict__ ao,
    const float* __restrict__ Wo, const float* __restrict__ bo,
    const float* __restrict__ g2, const float* __restrict__ b2,
    const float* __restrict__ W1, const float* __restrict__ bf1,
    const float* __restrict__ W2, const float* __restrict__ bf2,
    const float* __restrict__ Wp1, const float* __restrict__ bp1,
    const float* __restrict__ Wp2, const float* __restrict__ bp2,
    const float* __restrict__ Wz,
    float* __restrict__ out_x, float* __restrict__ p1, float* __restrict__ p2,
    float* __restrict__ T) {
  __shared__ float aos[2][D];
  __shared__ float x1s[2][D];
  __shared__ float nrm[2][D];
  __shared__ float x2s[2][D];
  __shared__ float hs[2][512];
  __shared__ __align__(16) float redbuf[4096];   // 16 KB, reused per phase
  __shared__ float ps_row[2][64];
  __shared__ float stat[2][2];
  f4* red4 = (f4*)redbuf;
  const int t = threadIdx.x;
  const int r0 = blockIdx.x * 2;
  // P1: load ao rows
  if (t < 256) { int r = t >> 7, c = t & 127; aos[r][c] = ao[(r0 + r) * D + c]; }
  __syncthreads();
  // P2: Wo partials — 32 col-groups(x4) × 16 k-chunks(of 8)
  {
    int cg = t & 31, q = t >> 5;
    f4 a0 = {0, 0, 0, 0}, a1 = {0, 0, 0, 0};
#pragma unroll
    for (int k = q * 8; k < q * 8 + 8; ++k) {
      f4 wv = ((const f4*)(Wo + k * D))[cg];
      float v0 = aos[0][k], v1 = aos[1][k];
      a0 += v0 * wv;
      a1 += v1 * wv;
    }
    red4[(q * 2 + 0) * 32 + cg] = a0;
    red4[(q * 2 + 1) * 32 + cg] = a1;
  }
  __syncthreads();
  // P3: x1 = x + Wo-proj + bo
  if (t < 256) {
    int r = t >> 7, c = t & 127;
    float a = x[(r0 + r) * D + c] + bo[c];
#pragma unroll
    for (int q = 0; q < 16; ++q) a += redbuf[q * 256 + r * 128 + c];
    x1s[r][c] = a;
  }
  __syncthreads();
  // P4: LN2 stats (wave w handles row w)
  if (t < 128) {
    int w = t >> 6, lane = t & 63;
    float a = x1s[w][lane], cc = x1s[w][lane + 64];
    float s = a + cc, s2 = a * a + cc * cc;
#pragma unroll
    for (int off = 32; off >= 1; off >>= 1) {
      s += __shfl_xor(s, off, 64);
      s2 += __shfl_xor(s2, off, 64);
    }
    if (lane == 0) {
      float mu = s * (1.0f / D);
      stat[w][0] = mu;
      stat[w][1] = rsqrtf(s2 * (1.0f / D) - mu * mu + 1e-5f);
    }
  }
  __syncthreads();
  // P5: normalize
  if (t < 256) {
    int r = t >> 7, c = t & 127;
    nrm[r][c] = (x1s[r][c] - stat[r][0]) * stat[r][1] * g2[c] + b2[c];
  }
  __syncthreads();
  // P6: FFN1 partials — 128 col-groups(x4) × 4 k-chunks(of 32)
  {
    int cg = t & 127, q = t >> 7;
    f4 a0 = {0, 0, 0, 0}, a1 = {0, 0, 0, 0};
#pragma unroll 4
    for (int k = q * 32; k < q * 32 + 32; ++k) {
      f4 wv = ((const f4*)(W1 + k * 512))[cg];
      float v0 = nrm[0][k], v1 = nrm[1][k];
      a0 += v0 * wv;
      a1 += v1 * wv;
    }
    red4[q * 256 + 0 * 128 + cg] = a0;
    red4[q * 256 + 1 * 128 + cg] = a1;
  }
  __syncthreads();
  // P7: reduce + gelu -> hs
  {
#pragma unroll
    for (int r = 0; r < 2; ++r) {
      float a = bf1[t];
#pragma unroll
      for (int q = 0; q < 4; ++q) a += redbuf[q * 1024 + r * 512 + t];
      hs[r][t] = 0.5f * a * (1.0f + erff(a * 0.70710678118654752f));
    }
  }
  __syncthreads();
  // P8: FFN2 partials — 32 col-groups(x4) × 16 k-chunks(of 32)
  {
    int cg = t & 31, q = t >> 5;
    f4 a0 = {0, 0, 0, 0}, a1 = {0, 0, 0, 0};
#pragma unroll 4
    for (int k = q * 32; k < q * 32 + 32; ++k) {
      f4 wv = ((const f4*)(W2 + k * D))[cg];
      float v0 = hs[0][k], v1 = hs[1][k];
      a0 += v0 * wv;
      a1 += v1 * wv;
    }
    red4[(q * 2 + 0) * 32 + cg] = a0;
    red4[(q * 2 + 1) * 32 + cg] = a1;
  }
  __syncthreads();
  // P9: x2 = x1 + FFN2 + bf2 ; write out_x
  if (t < 256) {
    int r = t >> 7, c = t & 127;
    float a = x1s[r][c] + bf2[c];
#pragma unroll
    for (int q = 0; q < 16; ++q) a += redbuf[q * 256 + r * 128 + c];
    x2s[r][c] = a;
    out_x[(r0 + r) * D + c] = a;
  }
  __syncthreads();
  // P10: p1/p2 partials — t = q*128 + r*64 + o, k-chunk of 32
  {
    int o = t & 63, r = (t >> 6) & 1, q = t >> 7;
    const float* W = (o < 32) ? Wp1 : Wp2;
    int cc = o & 31;
    float a = 0;
#pragma unroll
    for (int k = q * 32; k < q * 32 + 32; ++k) a += x2s[r][k] * W[k * DO + cc];
    redbuf[t] = a;
  }
  __syncthreads();
  // P11: reduce p-proj, write p1/p2, keep in LDS
  if (t < 128) {
    int r = t >> 6, o = t & 63;
    float a = redbuf[0 * 128 + r * 64 + o] + redbuf[1 * 128 + r * 64 + o] +
              redbuf[2 * 128 + r * 64 + o] + redbuf[3 * 128 + r * 64 + o] +
              ((o < 32) ? bp1[o] : bp2[o & 31]);
    ps_row[r][o] = a;
    if (o < 32) p1[(r0 + r) * DO + o] = a;
    else        p2[(r0 + r) * DO + (o & 31)] = a;
  }
  __syncthreads();
  // P12: T[r, idx] = sum_c p1[r][c] * Wz[c][idx] — float4 over idx
  {
    const f4* Wz4 = (const f4*)Wz;
    f4 a0 = {0, 0, 0, 0}, a1 = {0, 0, 0, 0};
#pragma unroll 8
    for (int cc = 0; cc < 32; ++cc) {
      f4 wv = Wz4[cc * 512 + t];
      float v0 = ps_row[0][cc], v1 = ps_row[1][cc];
      a0 += v0 * wv;
      a1 += v1 * wv;
    }
    ((f4*)T)[(size_t)(r0 + 0) * 512 + t] = a0;
    ((f4*)T)[(size_t)(r0 + 1) * 512 + t] = a1;
  }
}

// ---------------------------------------------------------------------------
// K6: z_out = LN(z + p2 @ T_i + bz).  Block per (b,i,j-tile of 80).
// lane = (jj,pq): all z/zout accesses f4 (16B/lane); T in LDS (8KB);
// LN reduce = 4 shuffles across the 16-lane group. ~40 VGPRs live, no spill.
// ---------------------------------------------------------------------------
__global__ __launch_bounds__(256) void k6_zout(
    const float* __restrict__ z, const float* __restrict__ T,
    const float* __restrict__ p2, const float* __restrict__ bz,
    const float* __restrict__ gp, const float* __restrict__ bp,
    float* __restrict__ zout) {
  __shared__ __align__(16) f4 tds[32][16];       // T[d][p4]: 8 KB
  __shared__ __align__(16) float p2s[80 * DO];   // 10 KB
  const int t = threadIdx.x;
  const int jt = blockIdx.x;       // 0..3: tile of 80 j's
  const int i = blockIdx.y, b = blockIdx.z;
  const size_t row = (size_t)(b * L + i);
  {  // stage T row (512 f4) and p2 tile (640 f4)
    const f4* Tsrc = (const f4*)(T + row * 2048);
    f4* tflat = (f4*)tds;
    tflat[t] = Tsrc[t];
    tflat[t + 256] = Tsrc[t + 256];
    const f4* psrc4 = (const f4*)(p2 + ((size_t)b * L + jt * 80) * DO);
    f4* p2s4 = (f4*)p2s;
    for (int q = t; q < 640; q += 256) p2s4[q] = psrc4[q];
  }
  const int w = t >> 6, lane = t & 63;
  const int jj = lane >> 4, pq = lane & 15;
  const f4 bz4 = ((const f4*)bz)[pq];
  const f4 g4 = ((const f4*)gp)[pq];
  const f4 b4 = ((const f4*)bp)[pq];
  __syncthreads();
  const float* zbase = z + (row * L + (size_t)jt * 80) * DP;
  float* obase = zout + (row * L + (size_t)jt * 80) * DP;
#pragma unroll
  for (int q = 0; q < 5; ++q) {
    const int jl = w * 20 + q * 4 + jj;          // local j in [0,80)
    f4 zv = ((const f4*)(zbase + jl * DP))[pq];
    f4 acc0 = bz4, acc1 = {0, 0, 0, 0};
#pragma unroll
    for (int d = 0; d < 32; d += 2) {
      acc0 += p2s[jl * DO + d] * tds[d][pq];
      acc1 += p2s[jl * DO + d + 1] * tds[d + 1][pq];
    }
    f4 y = zv + acc0 + acc1;
    float s = y.x + y.y + y.z + y.w;
    float s2 = y.x * y.x + y.y * y.y + y.z * y.z + y.w * y.w;
#pragma unroll
    for (int off = 8; off >= 1; off >>= 1) {     // reduce across 16-lane group
      s += __shfl_xor(s, off, 64);
      s2 += __shfl_xor(s2, off, 64);
    }
    float mu = s * (1.0f / DP);
    float var = s2 * (1.0f / DP) - mu * mu;
    float r = rsqrtf(var + 1e-5f);
    f4 out = (y - mu) * r * g4 + b4;
    ((f4*)(obase + jl * DP))[pq] = out;
  }
}

// ---------------------------------------------------------------------------
extern "C" void kernel_launch(void* const* d_in, const int* in_sizes, int n_in,
                              void* d_out, int out_size, void* d_ws, size_t ws_size,
                              hipStream_t stream) {
  const float* x      = (const float*)d_in[0];
  const float* z      = (const float*)d_in[1];
  const float* Wq     = (const float*)d_in[2];
  const float* Wk     = (const float*)d_in[3];
  const float* Wv     = (const float*)d_in[4];
  const float* Wb     = (const float*)d_in[5];
  const float* Wo     = (const float*)d_in[6];
  const float* bo     = (const float*)d_in[7];
  const float* ln1_g  = (const float*)d_in[8];
  const float* ln1_b  = (const float*)d_in[9];
  const float* W_ffn1 = (const float*)d_in[10];
  const float* b_ffn1 = (const float*)d_in[11];
  const float* W_ffn2 = (const float*)d_in[12];
  const float* b_ffn2 = (const float*)d_in[13];
  const float* ln2_g  = (const float*)d_in[14];
  const float* ln2_b  = (const float*)d_in[15];
  const float* Wp1    = (const float*)d_in[16];
  const float* bp1    = (const float*)d_in[17];
  const float* Wp2    = (const float*)d_in[18];
  const float* bp2    = (const float*)d_in[19];
  const float* Wz     = (const float*)d_in[20];
  const float* bz     = (const float*)d_in[21];
  const float* lnp_g  = (const float*)d_in[22];
  const float* lnp_b  = (const float*)d_in[23];

  float* ws   = (float*)d_ws;
  float* qkv  = ws;                   // 640*384
  float* bias = qkv + 245760;         // 2*8*320*320
  float* ao   = bias + 1638400;       // 640*128
  float* p1   = ao + 81920;           // 640*32
  float* p2   = p1 + 20480;           // 640*32
  float* T    = p2 + 20480;           // 640*2048

  float* out_x = (float*)d_out;
  float* out_z = out_x + 81920;

  hipLaunchKernelGGL(k12_qkv_bias, dim3(320 + 5 * L * NB), dim3(256), 0, stream,
                     x, Wq, Wk, Wv, ln1_g, ln1_b, qkv, z, Wb, bias);
  hipLaunchKernelGGL(k3_attn, dim3(L / 4, H, NB), dim3(256), 0, stream,
                     qkv, bias, ao);
  hipLaunchKernelGGL(k45_rowpass, dim3(NR / 2), dim3(512), 0, stream,
                     x, ao, Wo, bo, ln2_g, ln2_b, W_ffn1, b_ffn1,
                     W_ffn2, b_ffn2, Wp1, bp1, Wp2, bp2, Wz, out_x, p1, p2, T);
  hipLaunchKernelGGL(k6_zout, dim3(4, L, NB), dim3(256), 0, stream,
                     z, T, p2, bz, lnp_g, lnp_b, out_z);
}